// Round 10
// baseline (116.530 us; speedup 1.0000x reference)
//
#include <hip/hip_runtime.h>

#define NV 13824   // 24*24*24 voxels per batch
#define CCH 64     // channels
#define NB 2       // batch

// ---------------------------------------------------------------------------
// Kernel 1 (v6, unchanged): q/k/v projections, occupancy-first design.
// ---------------------------------------------------------------------------
__global__ __launch_bounds__(256) void qkv_kernel(
    const float* __restrict__ x,
    const float* __restrict__ Wq, const float* __restrict__ bq,
    const float* __restrict__ Wk, const float* __restrict__ bk,
    const float* __restrict__ Wv, const float* __restrict__ bv,
    float* __restrict__ qo, float* __restrict__ ko, float* __restrict__ vo)
{
    __shared__ float sb[3][64][20];   // padded: stride 20 -> no conflicts

    const int t    = threadIdx.x;
    const int bid  = blockIdx.x;
    const int lb   = (bid & 7) * 216 + (bid >> 3);  // bijective XCD chunking
    const int tile = lb >> 2;         // voxel tile 0..431
    const int cqg  = lb & 3;          // channel-quad group 0..3
    const int wid  = t >> 6;          // wave 0..3 (uniform)
    const int lane = t & 63;

    const int gr0 = tile * 64;        // global row base (64 | NV: no straddle)
    const int b   = gr0 / NV;
    const int nn  = gr0 - b * NV;
    const int n   = nn + lane;
    const int c0  = __builtin_amdgcn_readfirstlane(cqg * 16 + wid * 4);

    const float* xb = x + (size_t)b * CCH * NV + n;

    float xr[64];
    #pragma unroll
    for (int k = 0; k < 64; ++k) xr[k] = xb[(size_t)k * NV];

    const float* const Ws[3] = {Wq, Wk, Wv};
    const float* const bs[3] = {bq, bk, bv};

    #pragma unroll
    for (int m = 0; m < 3; ++m) {
        const float sc = (m == 0) ? 0.25f : 1.0f;   // fold hd^-0.5 into q
        #pragma unroll
        for (int j = 0; j < 4; ++j) {
            const float* row = Ws[m] + (size_t)(c0 + j) * 64;
            float a = bs[m][c0 + j];
            #pragma unroll
            for (int k4 = 0; k4 < 16; ++k4) {
                const float4 wv = *(const float4*)(row + k4 * 4);
                a += xr[k4 * 4 + 0] * wv.x + xr[k4 * 4 + 1] * wv.y
                   + xr[k4 * 4 + 2] * wv.z + xr[k4 * 4 + 3] * wv.w;
            }
            sb[m][lane][wid * 4 + j] = a * sc;
        }
    }
    __syncthreads();

    const int v = t >> 2;
    const int i = t & 3;
    float* const outs[3] = {qo, ko, vo};
    #pragma unroll
    for (int m = 0; m < 3; ++m) {
        const float4 o4 = *(const float4*)(&sb[m][v][i * 4]);
        *(float4*)(outs[m] + (size_t)(gr0 + v) * 64 + cqg * 16 + i * 4) = o4;
    }
}

// ---------------------------------------------------------------------------
// Kernel 2 (v5): tiled local attention.
// Block = (4x4x4 voxel tile) x (head-pair hp: channels hp*32..hp*32+31).
// Stage the 6^3 halo's k/v (128B/row) + tile q into LDS, ZERO-FILLED for
// OOB halo rows -> taps are unconditional and exactly reproduce the
// reference's zero-padded-k softmax (OOB logit = 0, v = 0). 8x tap reuse
// per staged row: global k/v traffic 382MB -> 48MB.
// LDS f4-slot swizzle (j ^ (row&7)) -> tap ds_read_b128 spread over all 8
// slot groups (minimum-phase). 72KB LDS -> 2 blocks/CU; 864 blocks.
// Thread = (vox 0..63, head-in-pair, dim-half); shfl_xor(1) combines halves.
// ---------------------------------------------------------------------------
__global__ __launch_bounds__(256) void attn_kernel(
    const float* __restrict__ x,
    const float* __restrict__ qw,
    const float* __restrict__ kw,
    const float* __restrict__ vw,
    float* __restrict__ out)
{
    __shared__ float4 sK[216 * 8];    // 27KB  [halo row][8 f4, swizzled]
    __shared__ float4 sV[216 * 8];    // 27KB
    __shared__ float4 sQ[64 * 8];     // 8KB   [tile vox][8 f4, swizzled]
    __shared__ float  so[64][33];     // 8.4KB output transpose (2/bank: free)

    const int t    = threadIdx.x;
    const int bid  = blockIdx.x;
    const int lb   = (bid & 7) * 108 + (bid >> 3);  // bijective XCD chunking
    const int hp   = lb & 1;                         // head pair 0/1
    const int tile = lb >> 1;                        // 0..431
    const int b    = tile / 216;
    const int tl   = tile - b * 216;
    const int d0   = (tl / 36) * 4;
    const int r0   = ((tl % 36) / 6) * 4;
    const int w0   = (tl % 6) * 4;

    const float* kwb = kw + (size_t)b * NV * 64 + hp * 32;
    const float* vwb = vw + (size_t)b * NV * 64 + hp * 32;
    const float* qwb = qw + (size_t)b * NV * 64 + hp * 32;

    // ---- stage halo k/v (216 rows x 8 f4), zero-filled OOB ----
    for (int g = t; g < 216 * 8; g += 256) {
        const int row = g >> 3;
        const int j   = g & 7;
        const int hz  = row / 36;
        const int hy  = (row % 36) / 6;
        const int hx  = row % 6;
        const int dd  = d0 - 1 + hz;
        const int rr  = r0 - 1 + hy;
        const int ww  = w0 - 1 + hx;
        const bool ok = ((unsigned)dd < 24u) & ((unsigned)rr < 24u) & ((unsigned)ww < 24u);
        const int n   = ok ? ((dd * 24 + rr) * 24 + ww) : 0;
        float4 kv = *(const float4*)(kwb + (size_t)n * 64 + j * 4);
        float4 vv = *(const float4*)(vwb + (size_t)n * 64 + j * 4);
        if (!ok) { kv = make_float4(0.f, 0.f, 0.f, 0.f); vv = kv; }
        const int dst = row * 8 + (j ^ (row & 7));
        sK[dst] = kv;
        sV[dst] = vv;
    }
    // ---- stage tile q (64 rows x 8 f4) ----
    for (int g = t; g < 64 * 8; g += 256) {
        const int row = g >> 3;
        const int j   = g & 7;
        const int n   = ((d0 + (row >> 4)) * 24 + (r0 + ((row >> 2) & 3))) * 24
                        + (w0 + (row & 3));
        sQ[row * 8 + (j ^ (row & 7))] =
            *(const float4*)(qwb + (size_t)n * 64 + j * 4);
    }
    __syncthreads();

    // ---- attention ----
    const int vox  = t >> 2;            // 0..63
    const int hh   = (t >> 1) & 1;      // head within pair
    const int half = t & 1;             // dim half (8 ch)
    const int j0   = hh * 4 + half * 2; // first f4 slot of this lane's 8 ch
    const int lz   = vox >> 4, ly = (vox >> 2) & 3, lx = vox & 3;

    const float4 q0 = sQ[vox * 8 + (j0 ^ (vox & 7))];
    const float4 q1 = sQ[vox * 8 + ((j0 + 1) ^ (vox & 7))];

    float logit[27];
    #pragma unroll
    for (int i3 = 0; i3 < 3; ++i3)
    #pragma unroll
    for (int j3 = 0; j3 < 3; ++j3)
    #pragma unroll
    for (int l3 = 0; l3 < 3; ++l3) {
        const int hidx = (lz + i3) * 36 + (ly + j3) * 6 + (lx + l3);
        const float4 k0 = sK[hidx * 8 + (j0 ^ (hidx & 7))];
        const float4 k1 = sK[hidx * 8 + ((j0 + 1) ^ (hidx & 7))];
        float a;
        a  = q0.x * k0.x + q0.y * k0.y + q0.z * k0.z + q0.w * k0.w;
        a += q1.x * k1.x + q1.y * k1.y + q1.z * k1.z + q1.w * k1.w;
        logit[(i3 * 3 + j3) * 3 + l3] = a;
    }
    #pragma unroll
    for (int j = 0; j < 27; ++j)
        logit[j] += __shfl_xor(logit[j], 1, 64);   // combine 8+8 dim halves

    float ssum = 0.f;
    #pragma unroll
    for (int j = 0; j < 27; ++j) {
        const float e = __expf(logit[j]);   // OOB rows: logit 0 -> exp 1 (ref)
        logit[j] = e;
        ssum += e;
    }
    const float inv = 1.f / ssum;

    float a0=0.f,a1=0.f,a2=0.f,a3=0.f,a4=0.f,a5=0.f,a6=0.f,a7=0.f;
    #pragma unroll
    for (int i3 = 0; i3 < 3; ++i3)
    #pragma unroll
    for (int j3 = 0; j3 < 3; ++j3)
    #pragma unroll
    for (int l3 = 0; l3 < 3; ++l3) {
        const int hidx = (lz + i3) * 36 + (ly + j3) * 6 + (lx + l3);
        const float p = logit[(i3 * 3 + j3) * 3 + l3];
        const float4 v0 = sV[hidx * 8 + (j0 ^ (hidx & 7))];
        const float4 v1 = sV[hidx * 8 + ((j0 + 1) ^ (hidx & 7))];
        a0 += p * v0.x; a1 += p * v0.y; a2 += p * v0.z; a3 += p * v0.w;
        a4 += p * v1.x; a5 += p * v1.y; a6 += p * v1.z; a7 += p * v1.w;
    }

    const int cb = hh * 16 + half * 8;   // channel base within pair
    so[vox][cb + 0] = a0 * inv;  so[vox][cb + 1] = a1 * inv;
    so[vox][cb + 2] = a2 * inv;  so[vox][cb + 3] = a3 * inv;
    so[vox][cb + 4] = a4 * inv;  so[vox][cb + 5] = a5 * inv;
    so[vox][cb + 6] = a6 * inv;  so[vox][cb + 7] = a7 * inv;
    __syncthreads();

    // ---- residual + channel-major store ----
    const int vv = t & 63;
    const int cg = t >> 6;               // 0..3 (8 ch each)
    const int n2 = ((d0 + (vv >> 4)) * 24 + (r0 + ((vv >> 2) & 3))) * 24
                   + (w0 + (vv & 3));
    const float* xb = x   + (size_t)b * CCH * NV + n2;
    float*       ob = out + (size_t)b * CCH * NV + n2;
    #pragma unroll
    for (int i = 0; i < 8; ++i) {
        const int c  = cg * 8 + i;            // within pair
        const int gc = hp * 32 + c;           // global channel
        ob[(size_t)gc * NV] = xb[(size_t)gc * NV] + so[vv][c];
    }
}

// ---------------------------------------------------------------------------
extern "C" void kernel_launch(void* const* d_in, const int* in_sizes, int n_in,
                              void* d_out, int out_size, void* d_ws, size_t ws_size,
                              hipStream_t stream) {
    const float* x  = (const float*)d_in[0];
    // d_in[1] = cemb, unused by the reference forward
    const float* Wq = (const float*)d_in[2];
    const float* bq = (const float*)d_in[3];
    const float* Wk = (const float*)d_in[4];
    const float* bk = (const float*)d_in[5];
    const float* Wv = (const float*)d_in[6];
    const float* bv = (const float*)d_in[7];
    float* out = (float*)d_out;

    float* ws = (float*)d_ws;
    const size_t RC = (size_t)NB * NV * CCH;   // 1,769,472 floats per tensor
    float* q = ws;
    float* k = ws + RC;
    float* v = ws + 2 * RC;

    const int nrows = NB * NV;                  // 27648

    qkv_kernel<<<nrows / 16, 256, 0, stream>>>(x, Wq, bq, Wk, bk, Wv, bv, q, k, v);
    attn_kernel<<<864, 256, 0, stream>>>(x, q, k, v, out);
}

// Round 11
// 107.883 us; speedup vs baseline: 1.0801x; 1.0801x over previous
//
#include <hip/hip_runtime.h>

#define NV 13824   // 24*24*24 voxels per batch
#define CCH 64     // channels
#define NB 2       // batch

// ---------------------------------------------------------------------------
// Kernel 1 (v7): q/k/v projections in the C^T orientation: C^T = W * X.
// X is [c][n] channel-major, so streaming along n gives DENSE reads: per
// c-step each wave reads one contiguous 1KB span. Outputs are row-major
// [n][64] pieces, stored as full-sector 32B chunks via an LDS transpose.
// Block = (32-output chunk: tensor m, ch0..ch0+31) x (256 voxels).
// Thread = 8 outputs x 4 voxels, acc = 8 x float4-over-n (natural FMA shape).
// W chunk (8KB) in LDS, wave-uniform broadcast reads; q-scale 0.25 and bias
// pre-folded into sW/sB. 648 blocks (= 8 XCD x 81), ~2.5 waves/SIMD,
// ~42KB LDS -> 3 blocks/CU. Est ~7-9us (VALU floor 4.3us).
// ---------------------------------------------------------------------------
__global__ __launch_bounds__(256) void qkv_kernel(
    const float* __restrict__ x,
    const float* __restrict__ Wq, const float* __restrict__ bq,
    const float* __restrict__ Wk, const float* __restrict__ bk,
    const float* __restrict__ Wv, const float* __restrict__ bv,
    float* __restrict__ qo, float* __restrict__ ko, float* __restrict__ vo)
{
    __shared__ float  sW[32 * 64];     // 8KB   [ol][c], pre-scaled
    __shared__ float  sB2[32];
    __shared__ float4 sO[32 * 65];     // 33.3KB [ol][n-f4], row pad 1 f4

    const int t   = threadIdx.x;
    const int bid = blockIdx.x;
    const int lb  = (bid & 7) * 81 + (bid >> 3);   // bijective XCD chunking
    const int oc  = lb % 6;            // output chunk 0..5
    const int nch = lb / 6;            // n-chunk 0..107 (256 voxels each)
    const int m   = oc >> 1;           // tensor 0=q 1=k 2=v
    const int ch0 = (oc & 1) * 32;     // channel base within tensor
    const int b   = nch / 54;
    const int nn  = (nch - b * 54) * 256;   // 256 | NV: no batch straddle
    const float sc = (m == 0) ? 0.25f : 1.0f;

    // stage W chunk (32 rows x 64) pre-scaled; dense contiguous reads
    {
        const float* const Ws[3] = {Wq, Wk, Wv};
        const float* const bs[3] = {bq, bk, bv};
        const float4* src = (const float4*)(Ws[m] + ch0 * 64);
        float4* dst = (float4*)sW;
        #pragma unroll
        for (int g = 0; g < 2; ++g) {
            float4 wv4 = src[g * 256 + t];
            wv4.x *= sc; wv4.y *= sc; wv4.z *= sc; wv4.w *= sc;
            dst[g * 256 + t] = wv4;
        }
        if (t < 32) sB2[t] = bs[m][ch0 + t] * sc;
    }
    __syncthreads();

    const int tn = t & 63;             // n-lane: 4 voxels at tn*4
    const int tw = t >> 6;             // wave id: outputs tw*8 .. tw*8+7
    const float* xp = x + (size_t)b * CCH * NV + nn + tn * 4;
    const float4* sW4 = (const float4*)sW;   // [ol][16 c-f4]

    float4 acc[8];
    #pragma unroll
    for (int i = 0; i < 8; ++i) acc[i] = make_float4(0.f, 0.f, 0.f, 0.f);

    #pragma unroll 4
    for (int c4 = 0; c4 < 16; ++c4) {
        // 8 wave-uniform W reads (broadcast), each covers 4 c-steps
        float4 w4[8];
        #pragma unroll
        for (int i = 0; i < 8; ++i) w4[i] = sW4[(tw * 8 + i) * 16 + c4];
        #pragma unroll
        for (int cc = 0; cc < 4; ++cc) {
            const float4 xv = *(const float4*)(xp + (size_t)(c4 * 4 + cc) * NV);
            #pragma unroll
            for (int i = 0; i < 8; ++i) {
                const float ws = (cc == 0) ? w4[i].x : (cc == 1) ? w4[i].y
                               : (cc == 2) ? w4[i].z : w4[i].w;
                acc[i].x += xv.x * ws; acc[i].y += xv.y * ws;
                acc[i].z += xv.z * ws; acc[i].w += xv.w * ws;
            }
        }
    }

    // deposit (+bias) into LDS transpose: dense b128, conflict-free
    #pragma unroll
    for (int i = 0; i < 8; ++i) {
        const int ol = tw * 8 + i;
        const float bb = sB2[ol];
        float4 a = acc[i];
        a.x += bb; a.y += bb; a.z += bb; a.w += bb;
        sO[ol * 65 + tn] = a;
    }
    __syncthreads();

    // gather o-direction float4s and store [n][ch0..ch0+32) pieces (32B full
    // sectors). 8 iterations x (4 strided b32 reads + 1 dense-ish f4 store).
    float* const outs[3] = {qo, ko, vo};
    const float* sOf = (const float*)sO;     // [ol][260 floats]
    float* ob = outs[m] + (size_t)(b * NV + nn) * 64 + ch0;
    #pragma unroll
    for (int it = 0; it < 8; ++it) {
        const int g   = it * 256 + t;
        const int n   = g >> 3;          // 0..255
        const int of4 = g & 7;           // which 4-channel group
        float4 o4;
        o4.x = sOf[(of4 * 4 + 0) * 260 + n];
        o4.y = sOf[(of4 * 4 + 1) * 260 + n];
        o4.z = sOf[(of4 * 4 + 2) * 260 + n];
        o4.w = sOf[(of4 * 4 + 3) * 260 + n];
        *(float4*)(ob + (size_t)n * 64 + of4 * 4) = o4;
    }
}

// ---------------------------------------------------------------------------
// Kernel 2 (v4, reverted from v5 which was +3.7us): local attention.
// Gather map: 8 lanes = one voxel's full 256B k/v row -> coalesced gathers.
// Branch-free taps (clamp + 0/1 mask) preserve zero-padded-k semantics.
// Dense I/O via padded LDS transpose so[32][65].
// ---------------------------------------------------------------------------
__global__ __launch_bounds__(256) void attn_kernel(
    const float* __restrict__ x,
    const float* __restrict__ qw,
    const float* __restrict__ kw,
    const float* __restrict__ vw,
    float* __restrict__ out)
{
    __shared__ float so[32][65];   // padded: conflict-free

    const int t    = threadIdx.x;
    const int bid  = blockIdx.x;
    const int lb   = (bid & 7) * 108 + (bid >> 3);   // bijective XCD chunking
    const int half = t & 1;
    const int head = (t >> 1) & 3;
    const int vb   = t >> 3;             // 0..31
    const int n0g  = lb * 32;            // 32 | NV -> no batch straddle
    const int gr   = n0g + vb;
    const int b    = gr / NV;
    const int n    = gr - b * NV;
    const int d    = n / 576;
    const int rem  = n - d * 576;
    const int r    = rem / 24;
    const int w    = rem - r * 24;
    const int coff = head * 16 + half * 8;

    // branch-free neighbor table: clamped index + 0/1 mask
    int   idx[27];
    float msk[27];
    #pragma unroll
    for (int i3 = 0; i3 < 3; ++i3)
    #pragma unroll
    for (int j3 = 0; j3 < 3; ++j3)
    #pragma unroll
    for (int l3 = 0; l3 < 3; ++l3) {
        const int dd = d + i3 - 1;
        const int rr = r + j3 - 1;
        const int ww = w + l3 - 1;
        const bool ok = ((unsigned)dd < 24u) & ((unsigned)rr < 24u) & ((unsigned)ww < 24u);
        const int jj = (i3 * 3 + j3) * 3 + l3;
        idx[jj] = ok ? ((dd * 24 + rr) * 24 + ww) : n;
        msk[jj] = ok ? 1.f : 0.f;
    }

    // q fragment (8 floats, already scaled by 0.25 in qkv)
    const float4* qp = (const float4*)(qw + (size_t)gr * 64 + coff);
    const float4 q0 = qp[0], q1 = qp[1];

    const float* kbase = kw + (size_t)b * NV * 64 + coff;

    // unconditional masked dot per tap
    float logit[27];
    #pragma unroll
    for (int j = 0; j < 27; ++j) {
        const float4* kp = (const float4*)(kbase + (size_t)idx[j] * 64);
        const float4 k0 = kp[0], k1 = kp[1];
        float a;
        a  = q0.x * k0.x + q0.y * k0.y + q0.z * k0.z + q0.w * k0.w;
        a += q1.x * k1.x + q1.y * k1.y + q1.z * k1.z + q1.w * k1.w;
        logit[j] = a * msk[j];
    }
    #pragma unroll
    for (int j = 0; j < 27; ++j)
        logit[j] += __shfl_xor(logit[j], 1, 64);   // combine 8+8 dim halves

    float ssum = 0.f;
    #pragma unroll
    for (int j = 0; j < 27; ++j) {
        const float e = __expf(logit[j]);   // OOB: exp(0)=1 participates
        logit[j] = e;
        ssum += e;
    }
    const float inv = 1.f / ssum;

    float a0=0.f,a1=0.f,a2=0.f,a3=0.f,a4=0.f,a5=0.f,a6=0.f,a7=0.f;
    const float* vbase = vw + (size_t)b * NV * 64 + coff;
    #pragma unroll
    for (int j = 0; j < 27; ++j) {
        const float p = logit[j] * msk[j];   // OOB contributes v = 0
        const float4* vp = (const float4*)(vbase + (size_t)idx[j] * 64);
        const float4 v0 = vp[0], v1 = vp[1];
        a0 += p * v0.x; a1 += p * v0.y; a2 += p * v0.z; a3 += p * v0.w;
        a4 += p * v1.x; a5 += p * v1.y; a6 += p * v1.z; a7 += p * v1.w;
    }

    // LDS transpose: each lane deposits its 8 channels (scaled by inv)
    so[vb][coff + 0] = a0 * inv;  so[vb][coff + 1] = a1 * inv;
    so[vb][coff + 2] = a2 * inv;  so[vb][coff + 3] = a3 * inv;
    so[vb][coff + 4] = a4 * inv;  so[vb][coff + 5] = a5 * inv;
    so[vb][coff + 6] = a6 * inv;  so[vb][coff + 7] = a7 * inv;
    __syncthreads();

    // dense store phase: lanes = 32 consecutive voxels, 8 channels each
    const int vv = t & 31;
    const int cg = t >> 5;
    const int bs = n0g / NV;
    const int nb0 = n0g - bs * NV;
    const float* xb = x   + (size_t)bs * CCH * NV + nb0 + vv;
    float*       ob = out + (size_t)bs * CCH * NV + nb0 + vv;
    #pragma unroll
    for (int i = 0; i < 8; ++i) {
        const int c = cg * 8 + i;
        ob[(size_t)c * NV] = xb[(size_t)c * NV] + so[vv][c];
    }
}

// ---------------------------------------------------------------------------
extern "C" void kernel_launch(void* const* d_in, const int* in_sizes, int n_in,
                              void* d_out, int out_size, void* d_ws, size_t ws_size,
                              hipStream_t stream) {
    const float* x  = (const float*)d_in[0];
    // d_in[1] = cemb, unused by the reference forward
    const float* Wq = (const float*)d_in[2];
    const float* bq = (const float*)d_in[3];
    const float* Wk = (const float*)d_in[4];
    const float* bk = (const float*)d_in[5];
    const float* Wv = (const float*)d_in[6];
    const float* bv = (const float*)d_in[7];
    float* out = (float*)d_out;

    float* ws = (float*)d_ws;
    const size_t RC = (size_t)NB * NV * CCH;   // 1,769,472 floats per tensor
    float* q = ws;
    float* k = ws + RC;
    float* v = ws + 2 * RC;

    qkv_kernel<<<648, 256, 0, stream>>>(x, Wq, bq, Wk, bk, Wv, bv, q, k, v);
    attn_kernel<<<864, 256, 0, stream>>>(x, q, k, v, out);
}